// Round 2
// baseline (303.343 us; speedup 1.0000x reference)
//
#include <hip/hip_runtime.h>

// ---------------------------------------------------------------------------
// GCN: out = spmm(A, relu(spmm(A, x)@w1 + b1)) @ w2 + b2
// Reordered: y1 = x@w1 ; h1 = relu(spmm(y1)+b1) ; y2 = h1@w2 ; out = spmm(y2)+b2
// R8: spmm_gemm2 phase 1 software-pipelined ACROSS rows (avg deg=16 -> per-row
//     loop drained the pipe every row). Iter i: prefetch ep[row i+2], issue
//     gathers[row i+1], FMA row i. Row bounds via lane-parallel rowptr + shfl.
// ---------------------------------------------------------------------------

typedef __bf16 v8bf __attribute__((ext_vector_type(8)));
typedef float  v4f  __attribute__((ext_vector_type(4)));

#define MAXB 800  // max buckets (N<=102400)

__device__ __forceinline__ unsigned short f2bf(float f) {
    unsigned u = __float_as_uint(f);
    unsigned r = u + 0x7fffu + ((u >> 16) & 1u);   // RNE
    return (unsigned short)(r >> 16);
}

// ---- hist + prep: bucket histogram, weight casts, sentinels ---------------
__global__ __launch_bounds__(256) void hist_prep(const int* __restrict__ arow,
                                                 int* __restrict__ counts, int E, int B,
                                                 const float* __restrict__ w1,
                                                 const float* __restrict__ w2,
                                                 unsigned short* __restrict__ w1T,
                                                 unsigned short* __restrict__ w2T,
                                                 int* __restrict__ rowptr,
                                                 int2* __restrict__ epkS, int N) {
    const int tid = threadIdx.x;
    // ---- prep slice (first ~100 blocks' threads) ----
    int gi = blockIdx.x * 256 + tid;
    if (gi < 16384) {                       // w1T[n*128+k] = w1[k*128+n]
        int n = gi >> 7, k = gi & 127;
        w1T[gi] = f2bf(w1[k * 128 + n]);
    } else if (gi < 24576) {                // w2T[n*128+k] = w2[k*64+n]
        int i2 = gi - 16384;
        int n = i2 >> 7, k = i2 & 127;
        w2T[i2] = f2bf(w2[k * 64 + n]);
    } else if (gi < 24576 + 32) {           // sentinels for spmm overread
        epkS[E + (gi - 24576)] = make_int2(0, 0);
    } else if (gi == 24576 + 32) {
        rowptr[N] = E;
    }
    // ---- histogram ----
    __shared__ int lh[MAXB];
    for (int i = tid; i < B; i += 256) lh[i] = 0;
    __syncthreads();
    const int base = blockIdx.x * 4096;
#pragma unroll
    for (int j = 0; j < 16; ++j) {
        int i = base + j * 256 + tid;
        if (i < E) atomicAdd(&lh[arow[i] >> 7], 1);
    }
    __syncthreads();
    for (int i = tid; i < B; i += 256) {
        int c = lh[i];
        if (c) atomicAdd(&counts[i], c);
    }
}

// ---- single-block exclusive scan over bucket counts -----------------------
__global__ __launch_bounds__(256) void scan_s(const int* __restrict__ counts,
                                              int* __restrict__ boff,
                                              int* __restrict__ gcursor, int B, int E) {
    __shared__ int lds[256];
    const int t = threadIdx.x;
    const int b0 = t * 4;
    int v[4];
    int s = 0;
#pragma unroll
    for (int j = 0; j < 4; ++j) {
        v[j] = (b0 + j < B) ? counts[b0 + j] : 0;
        s += v[j];
    }
    lds[t] = s;
    __syncthreads();
    for (int off = 1; off < 256; off <<= 1) {
        int tmp = 0;
        if (t >= off) tmp = lds[t - off];
        __syncthreads();
        if (t >= off) lds[t] += tmp;
        __syncthreads();
    }
    int run = (t > 0) ? lds[t - 1] : 0;
#pragma unroll
    for (int j = 0; j < 4; ++j) {
        if (b0 + j < B) {
            boff[b0 + j] = run;
            gcursor[b0 + j] = run;
        }
        run += v[j];
    }
    if (t == 255) boff[B] = E;
}

// ---- pass 1: bucket-order edges with LDS staging (coalesced out) ----------
__global__ __launch_bounds__(256) void partition_k(const int* __restrict__ arow,
                                                   const int* __restrict__ acol,
                                                   const float* __restrict__ aval,
                                                   int* __restrict__ gcursor,
                                                   int2* __restrict__ epk, int E, int B) {
    __shared__ int2 ldata[4096];
    __shared__ int ldest[4096];
    __shared__ int lhist[MAXB];
    __shared__ int lscan[MAXB];
    __shared__ int ldelta[MAXB];
    __shared__ int lcur[MAXB];
    __shared__ int stmp[256];
    const int tid = threadIdx.x;
    const int base = blockIdx.x * 4096;
    const int cnt = min(4096, E - base);

    for (int i = tid; i < MAXB; i += 256) {
        lhist[i] = 0;
        lcur[i] = 0;
    }
    __syncthreads();

    int rr[16];
#pragma unroll
    for (int j = 0; j < 16; ++j) {
        int i = base + j * 256 + tid;
        rr[j] = (i < E) ? arow[i] : -1;
        if (rr[j] >= 0) atomicAdd(&lhist[rr[j] >> 7], 1);
    }
    __syncthreads();

    const int b0 = tid * 4;
    int v[4];
    int s = 0;
#pragma unroll
    for (int j = 0; j < 4; ++j) {
        v[j] = (b0 + j < MAXB) ? lhist[b0 + j] : 0;
        s += v[j];
    }
    stmp[tid] = s;
    __syncthreads();
    for (int off = 1; off < 256; off <<= 1) {
        int tmp = 0;
        if (tid >= off) tmp = stmp[tid - off];
        __syncthreads();
        if (tid >= off) stmp[tid] += tmp;
        __syncthreads();
    }
    int run = (tid > 0) ? stmp[tid - 1] : 0;
#pragma unroll
    for (int j = 0; j < 4; ++j) {
        if (b0 + j < MAXB) lscan[b0 + j] = run;
        run += v[j];
    }
    __syncthreads();

    for (int b = tid; b < B; b += 256) {
        int c = lhist[b];
        if (c) ldelta[b] = atomicAdd(&gcursor[b], c) - lscan[b];
    }
    __syncthreads();

#pragma unroll
    for (int j = 0; j < 16; ++j) {
        int i = base + j * 256 + tid;
        if (i < E) {
            int r = rr[j];
            int b = r >> 7;
            int lp = atomicAdd(&lcur[b], 1);
            int slot = lscan[b] + lp;
            int pk = acol[i] | ((r & 127) << 17);
            ldata[slot] = make_int2(pk, __float_as_int(aval[i]));
            ldest[slot] = ldelta[b] + slot;
        }
    }
    __syncthreads();

    for (int s2 = tid; s2 < cnt; s2 += 256) epk[ldest[s2]] = ldata[s2];
}

// ---- MFMA GEMM body (global A): y_bf16[M x NC] = A[M x 128] @ W[128 x NC] -
template <int NC, bool AF32>
__device__ __forceinline__ void gemm_body(const void* __restrict__ A,
                                          const unsigned short* __restrict__ wT,
                                          unsigned short* __restrict__ y, int M,
                                          int bid, char* smem) {
    constexpr int KP = 136;
    constexpr int NT = NC / 16;
    unsigned short* wl = (unsigned short*)smem;
    const int tid = threadIdx.x;
    for (int idx = tid; idx < NC * 16; idx += 256) {
        int n = idx >> 4, kc = idx & 15;
        *(uint4*)&wl[n * KP + kc * 8] = *(const uint4*)&wT[n * 128 + kc * 8];
    }
    __syncthreads();

    const int wave = tid >> 6;
    const int lane = tid & 63;
    const int m = lane & 15;
    const int q = lane >> 4;
    const int rowbase = bid * 64 + wave * 16;
    const int rowc = min(rowbase + m, M - 1);

    v4f acc[NT] = {};
    union LU { uint4 qv; v8bf b; };

#pragma unroll
    for (int ks = 0; ks < 4; ++ks) {
        const int k0 = ks * 32 + q * 8;
        v8bf a;
        if (AF32) {
            const float* Ap = (const float*)A + (size_t)rowc * 128 + k0;
            float4 f0 = *(const float4*)Ap;
            float4 f1 = *(const float4*)(Ap + 4);
            union { unsigned short s[8]; v8bf b; } cv;
            cv.s[0] = f2bf(f0.x); cv.s[1] = f2bf(f0.y);
            cv.s[2] = f2bf(f0.z); cv.s[3] = f2bf(f0.w);
            cv.s[4] = f2bf(f1.x); cv.s[5] = f2bf(f1.y);
            cv.s[6] = f2bf(f1.z); cv.s[7] = f2bf(f1.w);
            a = cv.b;
        } else {
            LU lu;
            lu.qv = *(const uint4*)((const unsigned short*)A + (size_t)rowc * 128 + k0);
            a = lu.b;
        }
#pragma unroll
        for (int nt = 0; nt < NT; ++nt) {
            v8bf b = *(const v8bf*)&wl[(nt * 16 + m) * KP + k0];
            acc[nt] = __builtin_amdgcn_mfma_f32_16x16x32_bf16(a, b, acc[nt], 0, 0, 0);
        }
    }
#pragma unroll
    for (int nt = 0; nt < NT; ++nt) {
#pragma unroll
        for (int r = 0; r < 4; ++r) {
            int orow = rowbase + q * 4 + r;
            if (orow < M) y[(size_t)orow * NC + nt * 16 + m] = f2bf(acc[nt][r]);
        }
    }
}

// ---- fused: bucket_sort (blocks [0,B)) || gemm1 (blocks [B, B+gb)) --------
__global__ __launch_bounds__(256) void sort_gemm1(const int* __restrict__ boff,
                                                  const int2* __restrict__ epk,
                                                  int2* __restrict__ epkS,
                                                  int* __restrict__ rowptr, int N, int B,
                                                  const float* __restrict__ x,
                                                  const unsigned short* __restrict__ w1T,
                                                  unsigned short* __restrict__ y1b) {
    __shared__ __align__(16) char smem[34816];
    const int tid = threadIdx.x;
    if (blockIdx.x >= B) {
        gemm_body<128, true>(x, w1T, y1b, N, blockIdx.x - B, smem);
        return;
    }
    // ---- bucket_sort: per-bucket LDS counting sort by local row ----
    int2* sorted = (int2*)smem;                  // 4096 * 8 = 32768
    int*  sc     = (int*)(smem + 32768);         // 128 * 4
    int*  lcur   = (int*)(smem + 32768 + 512);   // 128 * 4
    const int b = blockIdx.x;
    const int s = boff[b], e = boff[b + 1];
    const int cnt = min(e - s, 4096);
    if (tid < 128) sc[tid] = 0;
    __syncthreads();
    for (int i = s + tid; i < e; i += 256) {
        int rl = (epk[i].x >> 17) & 127;
        atomicAdd(&sc[rl], 1);
    }
    __syncthreads();
    int hv = (tid < 128) ? sc[tid] : 0;
    for (int off = 1; off < 128; off <<= 1) {
        int add = 0;
        if (tid < 128 && tid >= off) add = sc[tid - off];
        __syncthreads();
        if (tid < 128 && tid >= off) sc[tid] += add;
        __syncthreads();
    }
    if (tid < 128) {
        int ex = sc[tid] - hv;  // exclusive
        lcur[tid] = ex;
        int r = b * 128 + tid;
        if (r < N) rowptr[r] = s + ex;
    }
    __syncthreads();
    for (int i = s + tid; i < e; i += 256) {
        int2 p = epk[i];
        int rl = (p.x >> 17) & 127;
        int slot = atomicAdd(&lcur[rl], 1);
        if (slot < 4096) sorted[slot] = make_int2(p.x & 0x1FFFF, p.y);
    }
    __syncthreads();
    for (int i = tid; i < cnt; i += 256) epkS[s + i] = sorted[i];
}

// ---- fused spmm1 + gemm2: block = 64 rows ---------------------------------
// Phase 1 (R8): wave w owns rows [r0, r0+16). Cross-row software pipeline:
//   iter i: (1) prefetch ep for row i+2, (2) issue gathers for row i+1 from
//   ep that arrived last iter, (3) FMA row i on gathers issued last iter,
//   (4) rare deg>32 serial remainder, (5) butterfly combine + h1 store.
//   16 lanes/edge-row (dwordx4 = 8 ch each), 4 edges per wave-load.
// Phase 2: y2 tile = h1_tile @ w2 via MFMA (unchanged).
__global__ __launch_bounds__(256) void spmm_gemm2(const int* __restrict__ rowptr,
                                                  const int2* __restrict__ ep,
                                                  const unsigned short* __restrict__ y1b,
                                                  const float* __restrict__ b1,
                                                  const unsigned short* __restrict__ w2T,
                                                  unsigned short* __restrict__ y2b, int N) {
    constexpr int KP = 136;
    __shared__ unsigned short h1[64 * KP];  // 17408 B
    const int tid = threadIdx.x;
    const int wave = tid >> 6, lane = tid & 63;
    const int eslot = lane >> 4;    // edge slot within group (0..3)
    const int cb = lane & 15;       // channel block: ch [8cb, 8cb+8)
    const int rowbase = blockIdx.x * 64;
    const unsigned* y32 = (const unsigned*)y1b;
    const float4 bb0 = *(const float4*)&b1[8 * cb];
    const float4 bb1 = *(const float4*)&b1[8 * cb + 4];

    const int r0 = rowbase + wave * 16;
    // lane l (l<=17) holds rowptr[r0+l]; bounds via shfl broadcast
    const int rp = rowptr[min(r0 + min((int)lane, 17), N)];
#define BND(i) __shfl(rp, (i))

    // ---- prologue: row 0 ep + gathers, row 1 ep ----
    int2 epc[8], epn[8];
    uint4 gcv[8];
    {
        const int s0 = BND(0), e0 = BND(1);
#pragma unroll
        for (int u = 0; u < 8; ++u) epc[u] = ep[s0 + 4 * u + eslot];
        const int s1 = BND(1);
#pragma unroll
        for (int u = 0; u < 8; ++u) epn[u] = ep[s1 + 4 * u + eslot];
#pragma unroll
        for (int u = 0; u < 8; ++u) {
            gcv[u] = make_uint4(0u, 0u, 0u, 0u);
            if (s0 + 4 * u < e0)
                gcv[u] = *(const uint4*)(y32 + (((unsigned)epc[u].x) << 6) + (cb << 2));
        }
    }

#pragma unroll 1
    for (int i = 0; i < 16; ++i) {
        const int si = BND(i), ei = BND(i + 1);
        // step 1: prefetch ep for row i+2 (sentinels cover overread past E)
        int2 epn2[8];
        if (i < 14) {
            const int s2 = BND(i + 2);
#pragma unroll
            for (int u = 0; u < 8; ++u) epn2[u] = ep[s2 + 4 * u + eslot];
        }
        // step 2: issue gathers for row i+1 (ep arrived last iter)
        uint4 gn[8];
        if (i < 15) {
            const int sn = BND(i + 1), en = BND(i + 2);
#pragma unroll
            for (int u = 0; u < 8; ++u) {
                gn[u] = make_uint4(0u, 0u, 0u, 0u);
                if (sn + 4 * u < en)
                    gn[u] = *(const uint4*)(y32 + (((unsigned)epn[u].x) << 6) + (cb << 2));
            }
        }
        // step 3: FMA row i (edges si..si+32 pipelined; gathers from last iter)
        float a[8] = {0.f, 0.f, 0.f, 0.f, 0.f, 0.f, 0.f, 0.f};
#pragma unroll
        for (int u = 0; u < 4; ++u) {
            const float v = (si + 4 * u + eslot < ei) ? __int_as_float(epc[u].y) : 0.f;
            a[0] += v * __uint_as_float(gcv[u].x << 16);
            a[1] += v * __uint_as_float(gcv[u].x & 0xffff0000u);
            a[2] += v * __uint_as_float(gcv[u].y << 16);
            a[3] += v * __uint_as_float(gcv[u].y & 0xffff0000u);
            a[4] += v * __uint_as_float(gcv[u].z << 16);
            a[5] += v * __uint_as_float(gcv[u].z & 0xffff0000u);
            a[6] += v * __uint_as_float(gcv[u].w << 16);
            a[7] += v * __uint_as_float(gcv[u].w & 0xffff0000u);
        }
        if (si + 16 < ei) {
#pragma unroll
            for (int u = 4; u < 8; ++u) {
                const float v = (si + 4 * u + eslot < ei) ? __int_as_float(epc[u].y) : 0.f;
                a[0] += v * __uint_as_float(gcv[u].x << 16);
                a[1] += v * __uint_as_float(gcv[u].x & 0xffff0000u);
                a[2] += v * __uint_as_float(gcv[u].y << 16);
                a[3] += v * __uint_as_float(gcv[u].y & 0xffff0000u);
                a[4] += v * __uint_as_float(gcv[u].z << 16);
                a[5] += v * __uint_as_float(gcv[u].z & 0xffff0000u);
                a[6] += v * __uint_as_float(gcv[u].w << 16);
                a[7] += v * __uint_as_float(gcv[u].w & 0xffff0000u);
            }
        }
        // step 4: remainder deg>32 (Poisson(16) tail, ~0.02% of rows)
        for (int j = si + 32; j < ei; j += 16) {
            int2 ec2[4];
#pragma unroll
            for (int k = 0; k < 4; ++k) ec2[k] = ep[j + 4 * k + eslot];
#pragma unroll
            for (int k = 0; k < 4; ++k) {
                uint4 g = make_uint4(0u, 0u, 0u, 0u);
                if (j + 4 * k < ei)
                    g = *(const uint4*)(y32 + (((unsigned)ec2[k].x) << 6) + (cb << 2));
                const float v = (j + 4 * k + eslot < ei) ? __int_as_float(ec2[k].y) : 0.f;
                a[0] += v * __uint_as_float(g.x << 16);
                a[1] += v * __uint_as_float(g.x & 0xffff0000u);
                a[2] += v * __uint_as_float(g.y << 16);
                a[3] += v * __uint_as_float(g.y & 0xffff0000u);
                a[4] += v * __uint_as_float(g.z << 16);
                a[5] += v * __uint_as_float(g.z & 0xffff0000u);
                a[6] += v * __uint_as_float(g.w << 16);
                a[7] += v * __uint_as_float(g.w & 0xffff0000u);
            }
        }
        // step 5: combine the 4 edge slots (butterfly over lane bits 4,5)
#pragma unroll
        for (int t = 0; t < 8; ++t) a[t] += __shfl_xor(a[t], 16);
#pragma unroll
        for (int t = 0; t < 8; ++t) a[t] += __shfl_xor(a[t], 32);
        if (lane < 16) {
            float f0 = fmaxf(a[0] + bb0.x, 0.f);
            float f1 = fmaxf(a[1] + bb0.y, 0.f);
            float f2 = fmaxf(a[2] + bb0.z, 0.f);
            float f3 = fmaxf(a[3] + bb0.w, 0.f);
            float f4 = fmaxf(a[4] + bb1.x, 0.f);
            float f5 = fmaxf(a[5] + bb1.y, 0.f);
            float f6 = fmaxf(a[6] + bb1.z, 0.f);
            float f7 = fmaxf(a[7] + bb1.w, 0.f);
            uint4 pk;
            pk.x = ((unsigned)f2bf(f1) << 16) | f2bf(f0);
            pk.y = ((unsigned)f2bf(f3) << 16) | f2bf(f2);
            pk.z = ((unsigned)f2bf(f5) << 16) | f2bf(f4);
            pk.w = ((unsigned)f2bf(f7) << 16) | f2bf(f6);
            *(uint4*)&h1[(wave * 16 + i) * KP + 8 * cb] = pk;
        }
        // rotate pipeline state
        if (i < 15) {
#pragma unroll
            for (int u = 0; u < 8; ++u) {
                epc[u] = epn[u];
                gcv[u] = gn[u];
            }
        }
        if (i < 14) {
#pragma unroll
            for (int u = 0; u < 8; ++u) epn[u] = epn2[u];
        }
    }
#undef BND
    __syncthreads();

    // ---- phase 2: MFMA ----
    const int m = lane & 15, q = lane >> 4;
    v4f acc[4] = {};
#pragma unroll
    for (int ks = 0; ks < 4; ++ks) {
        const int k0 = ks * 32 + q * 8;
        v8bf av = *(const v8bf*)&h1[(wave * 16 + m) * KP + k0];
#pragma unroll
        for (int nt = 0; nt < 4; ++nt) {
            v8bf b = *(const v8bf*)&w2T[(nt * 16 + m) * 128 + k0];
            acc[nt] = __builtin_amdgcn_mfma_f32_16x16x32_bf16(av, b, acc[nt], 0, 0, 0);
        }
    }
#pragma unroll
    for (int nt = 0; nt < 4; ++nt) {
#pragma unroll
        for (int r = 0; r < 4; ++r) {
            int orow = rowbase + wave * 16 + q * 4 + r;
            if (orow < N) y2b[(size_t)orow * 64 + nt * 16 + m] = f2bf(acc[nt][r]);
        }
    }
}

// ---- SPMM CH=64: vectorized gather, 8 lanes/row -> 8 edges per load -------
__global__ __launch_bounds__(256) void spmm64(const int* __restrict__ rowptr,
                                              const int2* __restrict__ ep,
                                              const unsigned short* __restrict__ yb,
                                              const float* __restrict__ bias,
                                              float* __restrict__ outp, int N) {
    const int row = (blockIdx.x * 256 + threadIdx.x) >> 6;
    const int lane = threadIdx.x & 63;
    if (row >= N) return;
    const int eslot = lane >> 3;    // edge slot within group (0..7)
    const int cb = lane & 7;        // channel block: ch [8cb, 8cb+8)
    const unsigned* y32 = (const unsigned*)yb;
    const int s = __builtin_amdgcn_readfirstlane(rowptr[row]);
    const int e = __builtin_amdgcn_readfirstlane(rowptr[row + 1]);
    float a[8] = {0.f, 0.f, 0.f, 0.f, 0.f, 0.f, 0.f, 0.f};
    int2 cur[2];
#pragma unroll
    for (int k = 0; k < 2; ++k) cur[k] = ep[s + 8 * k + eslot];
    for (int j = s; j < e; j += 16) {
        int2 nxt[2];
#pragma unroll
        for (int k = 0; k < 2; ++k) nxt[k] = ep[j + 16 + 8 * k + eslot];
        uint4 g[2];
        float v[2];
#pragma unroll
        for (int k = 0; k < 2; ++k) {
            v[k] = (j + 8 * k + eslot < e) ? __int_as_float(cur[k].y) : 0.f;
            if (j + 8 * k < e)
                g[k] = *(const uint4*)(y32 + (((unsigned)cur[k].x) << 5) + (cb << 2));
            else
                g[k] = make_uint4(0u, 0u, 0u, 0u);
        }
#pragma unroll
        for (int k = 0; k < 2; ++k) {
            a[0] += v[k] * __uint_as_float(g[k].x << 16);
            a[1] += v[k] * __uint_as_float(g[k].x & 0xffff0000u);
            a[2] += v[k] * __uint_as_float(g[k].y << 16);
            a[3] += v[k] * __uint_as_float(g[k].y & 0xffff0000u);
            a[4] += v[k] * __uint_as_float(g[k].z << 16);
            a[5] += v[k] * __uint_as_float(g[k].z & 0xffff0000u);
            a[6] += v[k] * __uint_as_float(g[k].w << 16);
            a[7] += v[k] * __uint_as_float(g[k].w & 0xffff0000u);
        }
#pragma unroll
        for (int k = 0; k < 2; ++k) cur[k] = nxt[k];
    }
    // combine the 8 edge slots: butterfly over lane bits 3,4,5
#pragma unroll
    for (int t = 0; t < 8; ++t) a[t] += __shfl_xor(a[t], 8);
#pragma unroll
    for (int t = 0; t < 8; ++t) a[t] += __shfl_xor(a[t], 16);
#pragma unroll
    for (int t = 0; t < 8; ++t) a[t] += __shfl_xor(a[t], 32);
    if (lane < 8) {
        const float4 c0 = *(const float4*)&bias[8 * cb];
        const float4 c1 = *(const float4*)&bias[8 * cb + 4];
        float4 o0 = make_float4(a[0] + c0.x, a[1] + c0.y, a[2] + c0.z, a[3] + c0.w);
        float4 o1 = make_float4(a[4] + c1.x, a[5] + c1.y, a[6] + c1.z, a[7] + c1.w);
        float* op = outp + (size_t)row * 64 + 8 * cb;
        *(float4*)op = o0;
        *(float4*)(op + 4) = o1;
    }
}

// ---------------------------------------------------------------------------
extern "C" void kernel_launch(void* const* d_in, const int* in_sizes, int n_in,
                              void* d_out, int out_size, void* d_ws, size_t ws_size,
                              hipStream_t stream) {
    const float* x    = (const float*)d_in[0];
    const int*   arow = (const int*)d_in[1];
    const int*   acol = (const int*)d_in[2];
    const float* aval = (const float*)d_in[3];
    const float* w1   = (const float*)d_in[4];
    const float* b1   = (const float*)d_in[5];
    const float* w2   = (const float*)d_in[6];
    const float* b2   = (const float*)d_in[7];
    float*       out  = (float*)d_out;

    const int N = in_sizes[0] / 128;   // 100000
    const int E = in_sizes[1];         // 1600000
    const int B = (N + 127) >> 7;      // 782 buckets of 128 rows

    char* p = (char*)d_ws;
    auto alloc = [&](size_t bytes) {
        char* r = p;
        p += (bytes + 255) & ~(size_t)255;
        return r;
    };
    int*            counts  = (int*)alloc((size_t)MAXB * 4);
    int*            boff    = (int*)alloc((size_t)(MAXB + 1) * 4);
    int*            gcursor = (int*)alloc((size_t)MAXB * 4);
    int*            rowptr  = (int*)alloc((size_t)(N + 1) * 4);
    int2*           epkS    = (int2*)alloc((size_t)(E + 32) * 8);
    unsigned short* w1T     = (unsigned short*)alloc(128 * 128 * 2);
    unsigned short* w2T     = (unsigned short*)alloc(64 * 128 * 2);
    unsigned short* y1b     = (unsigned short*)alloc((size_t)N * 128 * 2);
    int2*           epk     = (int2*)alloc((size_t)E * 8);
    unsigned short* y2b     = (unsigned short*)alloc((size_t)N * 64 * 2);

    const int gemm_blocks = (N + 63) / 64;   // 1563
    const int pb = (E + 4095) / 4096;        // 391

    hipMemsetAsync(counts, 0, (size_t)MAXB * 4, stream);
    hist_prep<<<pb, 256, 0, stream>>>(arow, counts, E, B, w1, w2, w1T, w2T,
                                      rowptr, epkS, N);
    scan_s<<<1, 256, 0, stream>>>(counts, boff, gcursor, B, E);
    partition_k<<<pb, 256, 0, stream>>>(arow, acol, aval, gcursor, epk, E, B);
    sort_gemm1<<<B + gemm_blocks, 256, 0, stream>>>(boff, epk, epkS, rowptr, N, B,
                                                    x, w1T, y1b);
    spmm_gemm2<<<gemm_blocks, 256, 0, stream>>>(rowptr, epkS, y1b, b1, w2T, y2b, N);
    const int spmm_blocks = (N + 3) / 4;
    spmm64<<<spmm_blocks, 256, 0, stream>>>(rowptr, epkS, y2b, b2, out, N);
}

// Round 5
// 280.859 us; speedup vs baseline: 1.0801x; 1.0801x over previous
//
#include <hip/hip_runtime.h>

// ---------------------------------------------------------------------------
// GCN: out = spmm(A, relu(spmm(A, x)@w1 + b1)) @ w2 + b2
// Reordered: y1 = x@w1 ; h1 = relu(spmm(y1)+b1) ; y2 = h1@w2 ; out = spmm(y2)+b2
// R10: R9b with corrected ds_read_b64_tr_b16 addressing. Semantic (from m156
//      inversion): per 16-lane group, the 16 8-B slots form a 128-B 4x16 bf16
//      tile; lane receives COLUMN = its own slot index (addr-tile_base)/8,
//      rows j=0..3. So lane (m,q) addr = NTc + h*1024 + q*256 + 8*m (+128 for
//      j=4..7). R9b's +2*m assumed private reads -> wrong columns -> absmax 29.
// ---------------------------------------------------------------------------

typedef __bf16 v8bf __attribute__((ext_vector_type(8)));
typedef float  v4f  __attribute__((ext_vector_type(4)));
typedef unsigned v2u __attribute__((ext_vector_type(2)));

#define AS1 __attribute__((address_space(1)))
#define AS3 __attribute__((address_space(3)))

#define MAXB 800  // max buckets (N<=102400)

__device__ __forceinline__ unsigned short f2bf(float f) {
    unsigned u = __float_as_uint(f);
    unsigned r = u + 0x7fffu + ((u >> 16) & 1u);   // RNE
    return (unsigned short)(r >> 16);
}

__device__ __forceinline__ unsigned ldsaddr(const void* p) {
    return (unsigned)(unsigned long long)(const AS3 char*)p;
}

// HW transpose read (cooperative per 16-lane group; see header comment)
__device__ __forceinline__ v2u tr16(unsigned a) {
    v2u d;
    asm volatile("ds_read_b64_tr_b16 %0, %1" : "=v"(d) : "v"(a));
    return d;
}

// ---- hist + prep: bucket histogram, weight casts, sentinels ---------------
__global__ __launch_bounds__(256) void hist_prep(const int* __restrict__ arow,
                                                 int* __restrict__ counts, int E, int B,
                                                 const float* __restrict__ w1,
                                                 const float* __restrict__ w2,
                                                 unsigned short* __restrict__ w1T,
                                                 unsigned short* __restrict__ w2T,
                                                 int* __restrict__ rowptr,
                                                 int2* __restrict__ epkS, int N) {
    const int tid = threadIdx.x;
    // ---- prep slice (first ~100 blocks' threads) ----
    int gi = blockIdx.x * 256 + tid;
    if (gi < 16384) {                       // w1T[n*128+k] = w1[k*128+n]
        int n = gi >> 7, k = gi & 127;
        w1T[gi] = f2bf(w1[k * 128 + n]);
    } else if (gi < 24576) {                // w2T[n*128+k] = w2[k*64+n]
        int i2 = gi - 16384;
        int n = i2 >> 7, k = i2 & 127;
        w2T[i2] = f2bf(w2[k * 64 + n]);
    } else if (gi < 24576 + 32) {           // sentinels for spmm overread
        epkS[E + (gi - 24576)] = make_int2(0, 0);
    } else if (gi == 24576 + 32) {
        rowptr[N] = E;
    }
    // ---- histogram ----
    __shared__ int lh[MAXB];
    for (int i = tid; i < B; i += 256) lh[i] = 0;
    __syncthreads();
    const int base = blockIdx.x * 4096;
#pragma unroll
    for (int j = 0; j < 16; ++j) {
        int i = base + j * 256 + tid;
        if (i < E) atomicAdd(&lh[arow[i] >> 7], 1);
    }
    __syncthreads();
    for (int i = tid; i < B; i += 256) {
        int c = lh[i];
        if (c) atomicAdd(&counts[i], c);
    }
}

// ---- single-block exclusive scan over bucket counts -----------------------
__global__ __launch_bounds__(256) void scan_s(const int* __restrict__ counts,
                                              int* __restrict__ boff,
                                              int* __restrict__ gcursor, int B, int E) {
    __shared__ int lds[256];
    const int t = threadIdx.x;
    const int b0 = t * 4;
    int v[4];
    int s = 0;
#pragma unroll
    for (int j = 0; j < 4; ++j) {
        v[j] = (b0 + j < B) ? counts[b0 + j] : 0;
        s += v[j];
    }
    lds[t] = s;
    __syncthreads();
    for (int off = 1; off < 256; off <<= 1) {
        int tmp = 0;
        if (t >= off) tmp = lds[t - off];
        __syncthreads();
        if (t >= off) lds[t] += tmp;
        __syncthreads();
    }
    int run = (t > 0) ? lds[t - 1] : 0;
#pragma unroll
    for (int j = 0; j < 4; ++j) {
        if (b0 + j < B) {
            boff[b0 + j] = run;
            gcursor[b0 + j] = run;
        }
        run += v[j];
    }
    if (t == 255) boff[B] = E;
}

// ---- pass 1: bucket-order edges with LDS staging (coalesced out) ----------
__global__ __launch_bounds__(256) void partition_k(const int* __restrict__ arow,
                                                   const int* __restrict__ acol,
                                                   const float* __restrict__ aval,
                                                   int* __restrict__ gcursor,
                                                   int2* __restrict__ epk, int E, int B) {
    __shared__ int2 ldata[4096];
    __shared__ int ldest[4096];
    __shared__ int lhist[MAXB];
    __shared__ int lscan[MAXB];
    __shared__ int ldelta[MAXB];
    __shared__ int lcur[MAXB];
    __shared__ int stmp[256];
    const int tid = threadIdx.x;
    const int base = blockIdx.x * 4096;
    const int cnt = min(4096, E - base);

    for (int i = tid; i < MAXB; i += 256) {
        lhist[i] = 0;
        lcur[i] = 0;
    }
    __syncthreads();

    int rr[16];
#pragma unroll
    for (int j = 0; j < 16; ++j) {
        int i = base + j * 256 + tid;
        rr[j] = (i < E) ? arow[i] : -1;
        if (rr[j] >= 0) atomicAdd(&lhist[rr[j] >> 7], 1);
    }
    __syncthreads();

    const int b0 = tid * 4;
    int v[4];
    int s = 0;
#pragma unroll
    for (int j = 0; j < 4; ++j) {
        v[j] = (b0 + j < MAXB) ? lhist[b0 + j] : 0;
        s += v[j];
    }
    stmp[tid] = s;
    __syncthreads();
    for (int off = 1; off < 256; off <<= 1) {
        int tmp = 0;
        if (tid >= off) tmp = stmp[tid - off];
        __syncthreads();
        if (tid >= off) stmp[tid] += tmp;
        __syncthreads();
    }
    int run = (tid > 0) ? stmp[tid - 1] : 0;
#pragma unroll
    for (int j = 0; j < 4; ++j) {
        if (b0 + j < MAXB) lscan[b0 + j] = run;
        run += v[j];
    }
    __syncthreads();

    for (int b = tid; b < B; b += 256) {
        int c = lhist[b];
        if (c) ldelta[b] = atomicAdd(&gcursor[b], c) - lscan[b];
    }
    __syncthreads();

#pragma unroll
    for (int j = 0; j < 16; ++j) {
        int i = base + j * 256 + tid;
        if (i < E) {
            int r = rr[j];
            int b = r >> 7;
            int lp = atomicAdd(&lcur[b], 1);
            int slot = lscan[b] + lp;
            int pk = acol[i] | ((r & 127) << 17);
            ldata[slot] = make_int2(pk, __float_as_int(aval[i]));
            ldest[slot] = ldelta[b] + slot;
        }
    }
    __syncthreads();

    for (int s2 = tid; s2 < cnt; s2 += 256) epk[ldest[s2]] = ldata[s2];
}

// ---- MFMA GEMM body (global A): y_bf16[M x NC] = A[M x 128] @ W[128 x NC] -
template <int NC, bool AF32>
__device__ __forceinline__ void gemm_body(const void* __restrict__ A,
                                          const unsigned short* __restrict__ wT,
                                          unsigned short* __restrict__ y, int M,
                                          int bid, char* smem) {
    constexpr int KP = 136;
    constexpr int NT = NC / 16;
    unsigned short* wl = (unsigned short*)smem;
    const int tid = threadIdx.x;
    for (int idx = tid; idx < NC * 16; idx += 256) {
        int n = idx >> 4, kc = idx & 15;
        *(uint4*)&wl[n * KP + kc * 8] = *(const uint4*)&wT[n * 128 + kc * 8];
    }
    __syncthreads();

    const int wave = tid >> 6;
    const int lane = tid & 63;
    const int m = lane & 15;
    const int q = lane >> 4;
    const int rowbase = bid * 64 + wave * 16;
    const int rowc = min(rowbase + m, M - 1);

    v4f acc[NT] = {};
    union LU { uint4 qv; v8bf b; };

#pragma unroll
    for (int ks = 0; ks < 4; ++ks) {
        const int k0 = ks * 32 + q * 8;
        v8bf a;
        if (AF32) {
            const float* Ap = (const float*)A + (size_t)rowc * 128 + k0;
            float4 f0 = *(const float4*)Ap;
            float4 f1 = *(const float4*)(Ap + 4);
            union { unsigned short s[8]; v8bf b; } cv;
            cv.s[0] = f2bf(f0.x); cv.s[1] = f2bf(f0.y);
            cv.s[2] = f2bf(f0.z); cv.s[3] = f2bf(f0.w);
            cv.s[4] = f2bf(f1.x); cv.s[5] = f2bf(f1.y);
            cv.s[6] = f2bf(f1.z); cv.s[7] = f2bf(f1.w);
            a = cv.b;
        } else {
            LU lu;
            lu.qv = *(const uint4*)((const unsigned short*)A + (size_t)rowc * 128 + k0);
            a = lu.b;
        }
#pragma unroll
        for (int nt = 0; nt < NT; ++nt) {
            v8bf b = *(const v8bf*)&wl[(nt * 16 + m) * KP + k0];
            acc[nt] = __builtin_amdgcn_mfma_f32_16x16x32_bf16(a, b, acc[nt], 0, 0, 0);
        }
    }
#pragma unroll
    for (int nt = 0; nt < NT; ++nt) {
#pragma unroll
        for (int r = 0; r < 4; ++r) {
            int orow = rowbase + q * 4 + r;
            if (orow < M) y[(size_t)orow * NC + nt * 16 + m] = f2bf(acc[nt][r]);
        }
    }
}

// ---- fused: bucket_sort (blocks [0,B)) || gemm1 (blocks [B, B+gb)) --------
__global__ __launch_bounds__(256) void sort_gemm1(const int* __restrict__ boff,
                                                  const int2* __restrict__ epk,
                                                  int2* __restrict__ epkS,
                                                  int* __restrict__ rowptr, int N, int B,
                                                  const float* __restrict__ x,
                                                  const unsigned short* __restrict__ w1T,
                                                  unsigned short* __restrict__ y1b) {
    __shared__ __align__(16) char smem[34816];
    const int tid = threadIdx.x;
    if (blockIdx.x >= B) {
        gemm_body<128, true>(x, w1T, y1b, N, blockIdx.x - B, smem);
        return;
    }
    // ---- bucket_sort: per-bucket LDS counting sort by local row ----
    int2* sorted = (int2*)smem;                  // 4096 * 8 = 32768
    int*  sc     = (int*)(smem + 32768);         // 128 * 4
    int*  lcur   = (int*)(smem + 32768 + 512);   // 128 * 4
    const int b = blockIdx.x;
    const int s = boff[b], e = boff[b + 1];
    const int cnt = min(e - s, 4096);
    if (tid < 128) sc[tid] = 0;
    __syncthreads();
    for (int i = s + tid; i < e; i += 256) {
        int rl = (epk[i].x >> 17) & 127;
        atomicAdd(&sc[rl], 1);
    }
    __syncthreads();
    int hv = (tid < 128) ? sc[tid] : 0;
    for (int off = 1; off < 128; off <<= 1) {
        int add = 0;
        if (tid < 128 && tid >= off) add = sc[tid - off];
        __syncthreads();
        if (tid < 128 && tid >= off) sc[tid] += add;
        __syncthreads();
    }
    if (tid < 128) {
        int ex = sc[tid] - hv;  // exclusive
        lcur[tid] = ex;
        int r = b * 128 + tid;
        if (r < N) rowptr[r] = s + ex;
    }
    __syncthreads();
    for (int i = s + tid; i < e; i += 256) {
        int2 p = epk[i];
        int rl = (p.x >> 17) & 127;
        int slot = atomicAdd(&lcur[rl], 1);
        if (slot < 4096) sorted[slot] = p;   // keep row-local bits in .x
    }
    __syncthreads();
    for (int i = tid; i < cnt; i += 256) epkS[s + i] = sorted[i];
}

// ---- fused spmm1 + gemm2: block = 64 rows ---------------------------------
// Phase 1: wave w owns rows [r0, r0+16). Per 32-edge chunk:
//   (a) 8x global_load_lds dwordx4: lane 2k+h sources y1b[col_k] bytes
//       [t*32+h*16, +16) -> LDS neigh tile [chhi=8][k=32][chlo=16] bf16.
//   (b) val tile V[16][32] built in LDS (hi+lo bf16 split), row from the
//       edge's row-local bits, k = edge slot.
//   (c) 16x tr16 (B-frags: lane(m,q) addr = tile+8m -> receives col m) +
//       2x ds_read_b128 (A-frags) -> 16 MFMA: acc(16x128) += V @ Nb.
// After all chunks: barrier, acc -> relu+bias -> h1 (aliases staging LDS),
// barrier, phase 2 MFMA y2 = h1 @ w2.
__global__ __launch_bounds__(256) void spmm_gemm2(const int* __restrict__ rowptr,
                                                  const int2* __restrict__ ep,
                                                  const unsigned short* __restrict__ y1b,
                                                  const float* __restrict__ b1,
                                                  const unsigned short* __restrict__ w2T,
                                                  unsigned short* __restrict__ y2b, int N) {
    constexpr int KP = 136;
    __shared__ __align__(1024) char smem[40960];  // 4 waves * (8K neigh + 2x1K val)
    const int tid = threadIdx.x;
    const int wave = tid >> 6, lane = tid & 63;
    char* NTc = smem + wave * 10240;
    char* AT0 = NTc + 8192;
    char* AT1 = NTc + 9216;
    const int rowbase = blockIdx.x * 64;
    const int r0 = rowbase + wave * 16;
    const int si = __builtin_amdgcn_readfirstlane(rowptr[min(r0, N)]);
    const int ei = __builtin_amdgcn_readfirstlane(rowptr[min(r0 + 16, N)]);
    const int m = lane & 15, q = lane >> 4;

    float b1v[8];
#pragma unroll
    for (int h = 0; h < 8; ++h) b1v[h] = b1[h * 16 + m];

    // tr-read: group-q tile at NTc + h*1024 + q*256 (+128); lane slot = 8*m
    const unsigned trB = ldsaddr(NTc) + (unsigned)(q * 256 + m * 8);

    v4f acc[8] = {};

    for (int cb = si; cb < ei; cb += 32) {
        const int2 pe = ep[cb + (lane & 31)];
        const int colg = __shfl(pe.x & 0x1FFFF, lane >> 1);
        const char* gp = (const char*)y1b + ((size_t)(unsigned)colg << 8) + ((lane & 1) << 4);
#pragma unroll
        for (int t = 0; t < 8; ++t)
            __builtin_amdgcn_global_load_lds((const AS1 unsigned*)(gp + t * 32),
                                             (AS3 unsigned*)(NTc + t * 1024),
                                             16, 0, 0);
        // val tiles: zero then scatter (same-wave LDS ops are in-order)
        const uint4 z4 = make_uint4(0u, 0u, 0u, 0u);
        *(uint4*)(AT0 + lane * 16) = z4;
        *(uint4*)(AT1 + lane * 16) = z4;
        if (lane < 32 && cb + lane < ei) {
            const float v = __int_as_float(pe.y);
            const unsigned short vh = f2bf(v);
            const float vhf = __uint_as_float((unsigned)vh << 16);
            const unsigned short vl = f2bf(v - vhf);
            const int rl4 = (pe.x >> 17) & 15;
            *(unsigned short*)(AT0 + rl4 * 64 + lane * 2) = vh;
            *(unsigned short*)(AT1 + rl4 * 64 + lane * 2) = vl;
        }
        asm volatile("s_waitcnt vmcnt(0)" ::: "memory");
        __builtin_amdgcn_sched_barrier(0);
        v2u tr0[8], tr1[8];
#pragma unroll
        for (int h = 0; h < 8; ++h) {
            tr0[h] = tr16(trB + h * 1024);
            tr1[h] = tr16(trB + h * 1024 + 128);
        }
        const v8bf avh = *(const v8bf*)(AT0 + m * 64 + q * 16);
        const v8bf avl = *(const v8bf*)(AT1 + m * 64 + q * 16);
        asm volatile("s_waitcnt lgkmcnt(0)" ::: "memory");
        __builtin_amdgcn_sched_barrier(0);
#pragma unroll
        for (int h = 0; h < 8; ++h) {
            union { unsigned u[4]; v8bf b; } bu;
            bu.u[0] = tr0[h][0]; bu.u[1] = tr0[h][1];
            bu.u[2] = tr1[h][0]; bu.u[3] = tr1[h][1];
            acc[h] = __builtin_amdgcn_mfma_f32_16x16x32_bf16(avh, bu.b, acc[h], 0, 0, 0);
            acc[h] = __builtin_amdgcn_mfma_f32_16x16x32_bf16(avl, bu.b, acc[h], 0, 0, 0);
        }
    }
    __syncthreads();
    // acc -> relu+bias -> h1 (aliases staging LDS; all staging dead here)
    unsigned short* h1 = (unsigned short*)smem;
#pragma unroll
    for (int h = 0; h < 8; ++h) {
#pragma unroll
        for (int r = 0; r < 4; ++r) {
            const float f = fmaxf(acc[h][r] + b1v[h], 0.f);
            h1[(wave * 16 + q * 4 + r) * KP + h * 16 + m] = f2bf(f);
        }
    }
    __syncthreads();

    // ---- phase 2: MFMA y2 = h1 @ w2 ----
    v4f acc2[4] = {};
#pragma unroll
    for (int ks = 0; ks < 4; ++ks) {
        const int k0 = ks * 32 + q * 8;
        v8bf av = *(const v8bf*)&h1[(wave * 16 + m) * KP + k0];
#pragma unroll
        for (int nt = 0; nt < 4; ++nt) {
            v8bf b = *(const v8bf*)&w2T[(nt * 16 + m) * 128 + k0];
            acc2[nt] = __builtin_amdgcn_mfma_f32_16x16x32_bf16(av, b, acc2[nt], 0, 0, 0);
        }
    }
#pragma unroll
    for (int nt = 0; nt < 4; ++nt) {
#pragma unroll
        for (int r = 0; r < 4; ++r) {
            int orow = rowbase + wave * 16 + q * 4 + r;
            if (orow < N) y2b[(size_t)orow * 64 + nt * 16 + m] = f2bf(acc2[nt][r]);
        }
    }
}

// ---- SPMM CH=64: vectorized gather, 8 lanes/row -> 8 edges per load -------
__global__ __launch_bounds__(256) void spmm64(const int* __restrict__ rowptr,
                                              const int2* __restrict__ ep,
                                              const unsigned short* __restrict__ yb,
                                              const float* __restrict__ bias,
                                              float* __restrict__ outp, int N) {
    const int row = (blockIdx.x * 256 + threadIdx.x) >> 6;
    const int lane = threadIdx.x & 63;
    if (row >= N) return;
    const int eslot = lane >> 3;    // edge slot within group (0..7)
    const int cb = lane & 7;        // channel block: ch [8cb, 8cb+8)
    const unsigned* y32 = (const unsigned*)yb;
    const int s = __builtin_amdgcn_readfirstlane(rowptr[row]);
    const int e = __builtin_amdgcn_readfirstlane(rowptr[row + 1]);
    float a[8] = {0.f, 0.f, 0.f, 0.f, 0.f, 0.f, 0.f, 0.f};
    int2 cur[2];
#pragma unroll
    for (int k = 0; k < 2; ++k) cur[k] = ep[s + 8 * k + eslot];
    for (int j = s; j < e; j += 16) {
        int2 nxt[2];
#pragma unroll
        for (int k = 0; k < 2; ++k) nxt[k] = ep[j + 16 + 8 * k + eslot];
        uint4 g[2];
        float v[2];
#pragma unroll
        for (int k = 0; k < 2; ++k) {
            v[k] = (j + 8 * k + eslot < e) ? __int_as_float(cur[k].y) : 0.f;
            if (j + 8 * k < e)
                g[k] = *(const uint4*)(y32 + (((unsigned)(cur[k].x & 0x1FFFF)) << 5) + (cb << 2));
            else
                g[k] = make_uint4(0u, 0u, 0u, 0u);
        }
#pragma unroll
        for (int k = 0; k < 2; ++k) {
            a[0] += v[k] * __uint_as_float(g[k].x << 16);
            a[1] += v[k] * __uint_as_float(g[k].x & 0xffff0000u);
            a[2] += v[k] * __uint_as_float(g[k].y << 16);
            a[3] += v[k] * __uint_as_float(g[k].y & 0xffff0000u);
            a[4] += v[k] * __uint_as_float(g[k].z << 16);
            a[5] += v[k] * __uint_as_float(g[k].z & 0xffff0000u);
            a[6] += v[k] * __uint_as_float(g[k].w << 16);
            a[7] += v[k] * __uint_as_float(g[k].w & 0xffff0000u);
        }
#pragma unroll
        for (int k = 0; k < 2; ++k) cur[k] = nxt[k];
    }
    // combine the 8 edge slots: butterfly over lane bits 3,4,5
#pragma unroll
    for (int t = 0; t < 8; ++t) a[t] += __shfl_xor(a[t], 8);
#pragma unroll
    for (int t = 0; t < 8; ++t) a[t] += __shfl_xor(a[t], 16);
#pragma unroll
    for (int t = 0; t < 8; ++t) a[t] += __shfl_xor(a[t], 32);
    if (lane < 8) {
        const float4 c0 = *(const float4*)&bias[8 * cb];
        const float4 c1 = *(const float4*)&bias[8 * cb + 4];
        float4 o0 = make_float4(a[0] + c0.x, a[1] + c0.y, a[2] + c0.z, a[3] + c0.w);
        float4 o1 = make_float4(a[4] + c1.x, a[5] + c1.y, a[6] + c1.z, a[7] + c1.w);
        float* op = outp + (size_t)row * 64 + 8 * cb;
        *(float4*)op = o0;
        *(float4*)(op + 4) = o1;
    }
}

// ---------------------------------------------------------------------------
extern "C" void kernel_launch(void* const* d_in, const int* in_sizes, int n_in,
                              void* d_out, int out_size, void* d_ws, size_t ws_size,
                              hipStream_t stream) {
    const float* x    = (const float*)d_in[0];
    const int*   arow = (const int*)d_in[1];
    const int*   acol = (const int*)d_in[2];
    const float* aval = (const float*)d_in[3];
    const float* w1   = (const float*)d_in[4];
    const float* b1   = (const float*)d_in[5];
    const float* w2   = (const float*)d_in[6];
    const float* b2   = (const float*)d_in[7];
    float*       out  = (float*)d_out;

    const int N = in_sizes[0] / 128;   // 100000
    const int E = in_sizes[1];         // 1600000
    const int B = (N + 127) >> 7;      // 782 buckets of 128 rows

    char* p = (char*)d_ws;
    auto alloc = [&](size_t bytes) {
        char* r = p;
        p += (bytes + 255) & ~(size_t)255;
        return r;
    };
    int*            counts  = (int*)alloc((size_t)MAXB * 4);
    int*            boff    = (int*)alloc((size_t)(MAXB + 1) * 4);
    int*            gcursor = (int*)alloc((size_t)MAXB * 4);
    int*            rowptr  = (int*)alloc((size_t)(N + 1) * 4);
    int2*           epkS    = (int2*)alloc((size_t)(E + 32) * 8);
    unsigned short* w1T     = (unsigned short*)alloc(128 * 128 * 2);
    unsigned short* w2T     = (unsigned short*)alloc(64 * 128 * 2);
    unsigned short* y1b     = (unsigned short*)alloc((size_t)N * 128 * 2);
    int2*           epk     = (int2*)alloc((size_t)E * 8);
    unsigned short* y2b     = (unsigned short*)alloc((size_t)N * 64 * 2);

    const int gemm_blocks = (N + 63) / 64;   // 1563
    const int pb = (E + 4095) / 4096;        // 391

    hipMemsetAsync(counts, 0, (size_t)MAXB * 4, stream);
    hist_prep<<<pb, 256, 0, stream>>>(arow, counts, E, B, w1, w2, w1T, w2T,
                                      rowptr, epkS, N);
    scan_s<<<1, 256, 0, stream>>>(counts, boff, gcursor, B, E);
    partition_k<<<pb, 256, 0, stream>>>(arow, acol, aval, gcursor, epk, E, B);
    sort_gemm1<<<B + gemm_blocks, 256, 0, stream>>>(boff, epk, epkS, rowptr, N, B,
                                                    x, w1T, y1b);
    spmm_gemm2<<<gemm_blocks, 256, 0, stream>>>(rowptr, epkS, y1b, b1, w2T, y2b, N);
    const int spmm_blocks = (N + 3) / 4;
    spmm64<<<spmm_blocks, 256, 0, stream>>>(rowptr, epkS, y2b, b2, out, N);
}

// Round 6
// 277.335 us; speedup vs baseline: 1.0938x; 1.0127x over previous
//
#include <hip/hip_runtime.h>

// ---------------------------------------------------------------------------
// GCN: out = spmm(A, relu(spmm(A, x)@w1 + b1)) @ w2 + b2
// Reordered: y1 = x@w1 ; h1 = relu(spmm(y1)+b1) ; y2 = h1@w2 ; out = spmm(y2)+b2
// R11: per-wave counted-vmcnt pipeline (T3/T4) for both gather kernels.
//   spmm_mfma_pipe<NT>: double-buffered neigh LDS, ep prefetched 2 chunks
//   ahead in VGPRs, DMA for chunk c+1 issued before computing chunk c,
//   s_waitcnt vmcnt(NT+1) (never 0 mid-loop). sched_barrier fences pin the
//   issue order so compiler loads can't break the manual count.
//   spmm_gemm2: NT=8, 2-wave blocks (36.9KB -> 4 blk/CU, 8KB in flight/wave).
//   spmm64: rebuilt on the same pipe, NT=4, 4-wave blocks (40KB -> 4 blk/CU).
// ---------------------------------------------------------------------------

typedef __bf16 v8bf __attribute__((ext_vector_type(8)));
typedef float  v4f  __attribute__((ext_vector_type(4)));
typedef unsigned v2u __attribute__((ext_vector_type(2)));

#define AS1 __attribute__((address_space(1)))
#define AS3 __attribute__((address_space(3)))

#define MAXB 800  // max buckets (N<=102400)

__device__ __forceinline__ unsigned short f2bf(float f) {
    unsigned u = __float_as_uint(f);
    unsigned r = u + 0x7fffu + ((u >> 16) & 1u);   // RNE
    return (unsigned short)(r >> 16);
}

__device__ __forceinline__ unsigned ldsaddr(const void* p) {
    return (unsigned)(unsigned long long)(const AS3 char*)p;
}

// HW transpose read (cooperative per 16-lane group): the group's 16 8-B slots
// form a 128-B 4x16 bf16 tile; lane receives column = its slot index.
__device__ __forceinline__ v2u tr16(unsigned a) {
    v2u d;
    asm volatile("ds_read_b64_tr_b16 %0, %1" : "=v"(d) : "v"(a));
    return d;
}

// ---- hist + prep: bucket histogram, weight casts, sentinels ---------------
__global__ __launch_bounds__(256) void hist_prep(const int* __restrict__ arow,
                                                 int* __restrict__ counts, int E, int B,
                                                 const float* __restrict__ w1,
                                                 const float* __restrict__ w2,
                                                 unsigned short* __restrict__ w1T,
                                                 unsigned short* __restrict__ w2T,
                                                 int* __restrict__ rowptr,
                                                 int2* __restrict__ epkS, int N) {
    const int tid = threadIdx.x;
    // ---- prep slice (first ~100 blocks' threads) ----
    int gi = blockIdx.x * 256 + tid;
    if (gi < 16384) {                       // w1T[n*128+k] = w1[k*128+n]
        int n = gi >> 7, k = gi & 127;
        w1T[gi] = f2bf(w1[k * 128 + n]);
    } else if (gi < 24576) {                // w2T[n*128+k] = w2[k*64+n]
        int i2 = gi - 16384;
        int n = i2 >> 7, k = i2 & 127;
        w2T[i2] = f2bf(w2[k * 64 + n]);
    } else if (gi < 24576 + 32) {           // sentinels for spmm overread
        epkS[E + (gi - 24576)] = make_int2(0, 0);
    } else if (gi == 24576 + 32) {
        rowptr[N] = E;
    }
    // ---- histogram ----
    __shared__ int lh[MAXB];
    for (int i = tid; i < B; i += 256) lh[i] = 0;
    __syncthreads();
    const int base = blockIdx.x * 4096;
#pragma unroll
    for (int j = 0; j < 16; ++j) {
        int i = base + j * 256 + tid;
        if (i < E) atomicAdd(&lh[arow[i] >> 7], 1);
    }
    __syncthreads();
    for (int i = tid; i < B; i += 256) {
        int c = lh[i];
        if (c) atomicAdd(&counts[i], c);
    }
}

// ---- single-block exclusive scan over bucket counts -----------------------
__global__ __launch_bounds__(256) void scan_s(const int* __restrict__ counts,
                                              int* __restrict__ boff,
                                              int* __restrict__ gcursor, int B, int E) {
    __shared__ int lds[256];
    const int t = threadIdx.x;
    const int b0 = t * 4;
    int v[4];
    int s = 0;
#pragma unroll
    for (int j = 0; j < 4; ++j) {
        v[j] = (b0 + j < B) ? counts[b0 + j] : 0;
        s += v[j];
    }
    lds[t] = s;
    __syncthreads();
    for (int off = 1; off < 256; off <<= 1) {
        int tmp = 0;
        if (t >= off) tmp = lds[t - off];
        __syncthreads();
        if (t >= off) lds[t] += tmp;
        __syncthreads();
    }
    int run = (t > 0) ? lds[t - 1] : 0;
#pragma unroll
    for (int j = 0; j < 4; ++j) {
        if (b0 + j < B) {
            boff[b0 + j] = run;
            gcursor[b0 + j] = run;
        }
        run += v[j];
    }
    if (t == 255) boff[B] = E;
}

// ---- pass 1: bucket-order edges with LDS staging (coalesced out) ----------
__global__ __launch_bounds__(256) void partition_k(const int* __restrict__ arow,
                                                   const int* __restrict__ acol,
                                                   const float* __restrict__ aval,
                                                   int* __restrict__ gcursor,
                                                   int2* __restrict__ epk, int E, int B) {
    __shared__ int2 ldata[4096];
    __shared__ int ldest[4096];
    __shared__ int lhist[MAXB];
    __shared__ int lscan[MAXB];
    __shared__ int ldelta[MAXB];
    __shared__ int lcur[MAXB];
    __shared__ int stmp[256];
    const int tid = threadIdx.x;
    const int base = blockIdx.x * 4096;
    const int cnt = min(4096, E - base);

    for (int i = tid; i < MAXB; i += 256) {
        lhist[i] = 0;
        lcur[i] = 0;
    }
    __syncthreads();

    int rr[16];
#pragma unroll
    for (int j = 0; j < 16; ++j) {
        int i = base + j * 256 + tid;
        rr[j] = (i < E) ? arow[i] : -1;
        if (rr[j] >= 0) atomicAdd(&lhist[rr[j] >> 7], 1);
    }
    __syncthreads();

    const int b0 = tid * 4;
    int v[4];
    int s = 0;
#pragma unroll
    for (int j = 0; j < 4; ++j) {
        v[j] = (b0 + j < MAXB) ? lhist[b0 + j] : 0;
        s += v[j];
    }
    stmp[tid] = s;
    __syncthreads();
    for (int off = 1; off < 256; off <<= 1) {
        int tmp = 0;
        if (tid >= off) tmp = stmp[tid - off];
        __syncthreads();
        if (tid >= off) stmp[tid] += tmp;
        __syncthreads();
    }
    int run = (tid > 0) ? stmp[tid - 1] : 0;
#pragma unroll
    for (int j = 0; j < 4; ++j) {
        if (b0 + j < MAXB) lscan[b0 + j] = run;
        run += v[j];
    }
    __syncthreads();

    for (int b = tid; b < B; b += 256) {
        int c = lhist[b];
        if (c) ldelta[b] = atomicAdd(&gcursor[b], c) - lscan[b];
    }
    __syncthreads();

#pragma unroll
    for (int j = 0; j < 16; ++j) {
        int i = base + j * 256 + tid;
        if (i < E) {
            int r = rr[j];
            int b = r >> 7;
            int lp = atomicAdd(&lcur[b], 1);
            int slot = lscan[b] + lp;
            int pk = acol[i] | ((r & 127) << 17);
            ldata[slot] = make_int2(pk, __float_as_int(aval[i]));
            ldest[slot] = ldelta[b] + slot;
        }
    }
    __syncthreads();

    for (int s2 = tid; s2 < cnt; s2 += 256) epk[ldest[s2]] = ldata[s2];
}

// ---- MFMA GEMM body (global A): y_bf16[M x NC] = A[M x 128] @ W[128 x NC] -
template <int NC, bool AF32>
__device__ __forceinline__ void gemm_body(const void* __restrict__ A,
                                          const unsigned short* __restrict__ wT,
                                          unsigned short* __restrict__ y, int M,
                                          int bid, char* smem) {
    constexpr int KP = 136;
    constexpr int NT = NC / 16;
    unsigned short* wl = (unsigned short*)smem;
    const int tid = threadIdx.x;
    for (int idx = tid; idx < NC * 16; idx += 256) {
        int n = idx >> 4, kc = idx & 15;
        *(uint4*)&wl[n * KP + kc * 8] = *(const uint4*)&wT[n * 128 + kc * 8];
    }
    __syncthreads();

    const int wave = tid >> 6;
    const int lane = tid & 63;
    const int m = lane & 15;
    const int q = lane >> 4;
    const int rowbase = bid * 64 + wave * 16;
    const int rowc = min(rowbase + m, M - 1);

    v4f acc[NT] = {};
    union LU { uint4 qv; v8bf b; };

#pragma unroll
    for (int ks = 0; ks < 4; ++ks) {
        const int k0 = ks * 32 + q * 8;
        v8bf a;
        if (AF32) {
            const float* Ap = (const float*)A + (size_t)rowc * 128 + k0;
            float4 f0 = *(const float4*)Ap;
            float4 f1 = *(const float4*)(Ap + 4);
            union { unsigned short s[8]; v8bf b; } cv;
            cv.s[0] = f2bf(f0.x); cv.s[1] = f2bf(f0.y);
            cv.s[2] = f2bf(f0.z); cv.s[3] = f2bf(f0.w);
            cv.s[4] = f2bf(f1.x); cv.s[5] = f2bf(f1.y);
            cv.s[6] = f2bf(f1.z); cv.s[7] = f2bf(f1.w);
            a = cv.b;
        } else {
            LU lu;
            lu.qv = *(const uint4*)((const unsigned short*)A + (size_t)rowc * 128 + k0);
            a = lu.b;
        }
#pragma unroll
        for (int nt = 0; nt < NT; ++nt) {
            v8bf b = *(const v8bf*)&wl[(nt * 16 + m) * KP + k0];
            acc[nt] = __builtin_amdgcn_mfma_f32_16x16x32_bf16(a, b, acc[nt], 0, 0, 0);
        }
    }
#pragma unroll
    for (int nt = 0; nt < NT; ++nt) {
#pragma unroll
        for (int r = 0; r < 4; ++r) {
            int orow = rowbase + q * 4 + r;
            if (orow < M) y[(size_t)orow * NC + nt * 16 + m] = f2bf(acc[nt][r]);
        }
    }
}

// ---- fused: bucket_sort (blocks [0,B)) || gemm1 (blocks [B, B+gb)) --------
__global__ __launch_bounds__(256) void sort_gemm1(const int* __restrict__ boff,
                                                  const int2* __restrict__ epk,
                                                  int2* __restrict__ epkS,
                                                  int* __restrict__ rowptr, int N, int B,
                                                  const float* __restrict__ x,
                                                  const unsigned short* __restrict__ w1T,
                                                  unsigned short* __restrict__ y1b) {
    __shared__ __align__(16) char smem[34816];
    const int tid = threadIdx.x;
    if (blockIdx.x >= B) {
        gemm_body<128, true>(x, w1T, y1b, N, blockIdx.x - B, smem);
        return;
    }
    // ---- bucket_sort: per-bucket LDS counting sort by local row ----
    int2* sorted = (int2*)smem;                  // 4096 * 8 = 32768
    int*  sc     = (int*)(smem + 32768);         // 128 * 4
    int*  lcur   = (int*)(smem + 32768 + 512);   // 128 * 4
    const int b = blockIdx.x;
    const int s = boff[b], e = boff[b + 1];
    const int cnt = min(e - s, 4096);
    if (tid < 128) sc[tid] = 0;
    __syncthreads();
    for (int i = s + tid; i < e; i += 256) {
        int rl = (epk[i].x >> 17) & 127;
        atomicAdd(&sc[rl], 1);
    }
    __syncthreads();
    int hv = (tid < 128) ? sc[tid] : 0;
    for (int off = 1; off < 128; off <<= 1) {
        int add = 0;
        if (tid < 128 && tid >= off) add = sc[tid - off];
        __syncthreads();
        if (tid < 128 && tid >= off) sc[tid] += add;
        __syncthreads();
    }
    if (tid < 128) {
        int ex = sc[tid] - hv;  // exclusive
        lcur[tid] = ex;
        int r = b * 128 + tid;
        if (r < N) rowptr[r] = s + ex;
    }
    __syncthreads();
    for (int i = s + tid; i < e; i += 256) {
        int2 p = epk[i];
        int rl = (p.x >> 17) & 127;
        int slot = atomicAdd(&lcur[rl], 1);
        if (slot < 4096) sorted[slot] = p;   // keep row-local bits in .x
    }
    __syncthreads();
    for (int i = tid; i < cnt; i += 256) epkS[s + i] = sorted[i];
}

// ---- pipelined gather-DMA + MFMA segmented reduction (per-wave) -----------
// NT t-blocks of 1024B (NT=8: 256B rows, NT=4: 128B rows). Chunk = 32 edges.
// Double-buffered NB0/NB1; ep prefetched 2 chunks ahead; counted vmcnt.
template <int NT>
__device__ __forceinline__ void issue_dma(const unsigned short* __restrict__ yb,
                                          int colg, int lane, char* NB) {
    const char* gp = (const char*)yb + ((size_t)(unsigned)colg << (NT == 8 ? 8 : 7)) +
                     ((lane & 1) << 4);
#pragma unroll
    for (int t = 0; t < NT; ++t)
        __builtin_amdgcn_global_load_lds((const AS1 unsigned*)(gp + t * 32),
                                         (AS3 unsigned*)(NB + t * 1024), 16, 0, 0);
}

template <int NT>
__device__ __forceinline__ void spmm_mfma_pipe(int si, int ei, int E,
                                               const int2* __restrict__ ep,
                                               const unsigned short* __restrict__ yb,
                                               char* NB0, char* NB1, char* AT0, char* AT1,
                                               int lane, v4f* acc) {
    const int m = lane & 15, q = lane >> 4;
    const int l31 = lane & 31;
    const unsigned trBo = (unsigned)(q * 256 + m * 8);
    const int nch = (ei - si + 31) >> 5;
    if (nch <= 0) return;
    // prologue: pe for chunk0 (wait), DMA0, pe for chunk1 (in flight)
    int2 peA = ep[min(si + l31, E + 31)];
    {
        int colg0 = __shfl(peA.x & 0x1FFFF, lane >> 1);
        issue_dma<NT>(yb, colg0, lane, NB0);
    }
    int2 peB = ep[min(si + 32 + l31, E + 31)];
#pragma unroll 1
    for (int c = 0; c < nch; ++c) {
        char* curN = (c & 1) ? NB1 : NB0;
        char* nxtN = (c & 1) ? NB0 : NB1;
        const int cb = si + c * 32;
        const bool more = (c + 1 < nch);
        // ep for chunk c+2 -- issued BEFORE DMA c+1 so it sits under the count
        int2 peC = ep[min(cb + 64 + l31, E + 31)];
        __builtin_amdgcn_sched_barrier(0);
        if (more) {
            int colgN = __shfl(peB.x & 0x1FFFF, lane >> 1);  // waits peB only
            issue_dma<NT>(yb, colgN, lane, nxtN);
        }
        __builtin_amdgcn_sched_barrier(0);
        // val tile for chunk c (from peA; same-wave LDS ops are in-order)
        const uint4 z4 = make_uint4(0u, 0u, 0u, 0u);
        *(uint4*)(AT0 + lane * 16) = z4;
        *(uint4*)(AT1 + lane * 16) = z4;
        if (lane < 32 && cb + l31 < ei) {
            const float v = __int_as_float(peA.y);
            const unsigned short vh = f2bf(v);
            const float vhf = __uint_as_float((unsigned)vh << 16);
            const unsigned short vl = f2bf(v - vhf);
            const int rl4 = (peA.x >> 17) & 15;
            *(unsigned short*)(AT0 + rl4 * 64 + l31 * 2) = vh;
            *(unsigned short*)(AT1 + rl4 * 64 + l31 * 2) = vl;
        }
        // wait for DMA c; leave DMA c+1 (NT) + peC (1) in flight
        if (more) {
            if constexpr (NT == 8) asm volatile("s_waitcnt vmcnt(9)" ::: "memory");
            else                   asm volatile("s_waitcnt vmcnt(5)" ::: "memory");
        } else {
            asm volatile("s_waitcnt vmcnt(0)" ::: "memory");
        }
        __builtin_amdgcn_sched_barrier(0);
        const unsigned trB = ldsaddr(curN) + trBo;
        v2u tr0[NT], tr1[NT];
#pragma unroll
        for (int h = 0; h < NT; ++h) {
            tr0[h] = tr16(trB + h * 1024);
            tr1[h] = tr16(trB + h * 1024 + 128);
        }
        const v8bf avh = *(const v8bf*)(AT0 + m * 64 + q * 16);
        const v8bf avl = *(const v8bf*)(AT1 + m * 64 + q * 16);
        asm volatile("s_waitcnt lgkmcnt(0)" ::: "memory");
        __builtin_amdgcn_sched_barrier(0);
#pragma unroll
        for (int h = 0; h < NT; ++h) {
            union { unsigned u[4]; v8bf b; } bu;
            bu.u[0] = tr0[h][0]; bu.u[1] = tr0[h][1];
            bu.u[2] = tr1[h][0]; bu.u[3] = tr1[h][1];
            acc[h] = __builtin_amdgcn_mfma_f32_16x16x32_bf16(avh, bu.b, acc[h], 0, 0, 0);
            acc[h] = __builtin_amdgcn_mfma_f32_16x16x32_bf16(avl, bu.b, acc[h], 0, 0, 0);
        }
        peA = peB;
        peB = peC;
    }
}

// ---- fused spmm1 + gemm2: block = 2 waves x 16 rows = 32 rows -------------
__global__ __launch_bounds__(128) void spmm_gemm2(const int* __restrict__ rowptr,
                                                  const int2* __restrict__ ep,
                                                  const unsigned short* __restrict__ y1b,
                                                  const float* __restrict__ b1,
                                                  const unsigned short* __restrict__ w2T,
                                                  unsigned short* __restrict__ y2b,
                                                  int N, int E) {
    constexpr int KP = 136;
    __shared__ __align__(1024) char smem[36864];  // 2 waves * (2x8K NB + 2x1K AT)
    const int tid = threadIdx.x;
    const int wave = tid >> 6, lane = tid & 63;
    char* W = smem + wave * 18432;
    const int rowbase = blockIdx.x * 32;
    const int r0 = rowbase + wave * 16;
    const int si = __builtin_amdgcn_readfirstlane(rowptr[min(r0, N)]);
    const int ei = __builtin_amdgcn_readfirstlane(rowptr[min(r0 + 16, N)]);
    const int m = lane & 15, q = lane >> 4;

    v4f acc[8] = {};
    spmm_mfma_pipe<8>(si, ei, E, ep, y1b, W, W + 8192, W + 16384, W + 17408, lane, acc);
    __syncthreads();
    // acc -> relu+bias -> h1 (aliases staging LDS; all staging drained)
    unsigned short* h1 = (unsigned short*)smem;   // 32 rows * KP
#pragma unroll
    for (int h = 0; h < 8; ++h) {
        const float bv = b1[h * 16 + m];
#pragma unroll
        for (int r = 0; r < 4; ++r) {
            const float f = fmaxf(acc[h][r] + bv, 0.f);
            h1[(wave * 16 + q * 4 + r) * KP + h * 16 + m] = f2bf(f);
        }
    }
    __syncthreads();

    // ---- phase 2: MFMA y2 = h1 @ w2 ----
    v4f acc2[4] = {};
#pragma unroll
    for (int ks = 0; ks < 4; ++ks) {
        const int k0 = ks * 32 + q * 8;
        v8bf av = *(const v8bf*)&h1[(wave * 16 + m) * KP + k0];
#pragma unroll
        for (int nt = 0; nt < 4; ++nt) {
            v8bf b = *(const v8bf*)&w2T[(nt * 16 + m) * 128 + k0];
            acc2[nt] = __builtin_amdgcn_mfma_f32_16x16x32_bf16(av, b, acc2[nt], 0, 0, 0);
        }
    }
#pragma unroll
    for (int nt = 0; nt < 4; ++nt) {
#pragma unroll
        for (int r = 0; r < 4; ++r) {
            int orow = rowbase + wave * 16 + q * 4 + r;
            if (orow < N) y2b[(size_t)orow * 64 + nt * 16 + m] = f2bf(acc2[nt][r]);
        }
    }
}

// ---- SPMM CH=64 (layer-2 aggregate): same pipe, NT=4, f32 + bias out ------
__global__ __launch_bounds__(256) void spmm64(const int* __restrict__ rowptr,
                                              const int2* __restrict__ ep,
                                              const unsigned short* __restrict__ yb,
                                              const float* __restrict__ bias,
                                              float* __restrict__ outp, int N, int E) {
    __shared__ __align__(1024) char smem[40960];  // 4 waves * (2x4K NB + 2x1K AT)
    const int tid = threadIdx.x;
    const int wave = tid >> 6, lane = tid & 63;
    char* W = smem + wave * 10240;
    const int r0 = blockIdx.x * 64 + wave * 16;
    const int si = __builtin_amdgcn_readfirstlane(rowptr[min(r0, N)]);
    const int ei = __builtin_amdgcn_readfirstlane(rowptr[min(r0 + 16, N)]);
    const int m = lane & 15, q = lane >> 4;

    v4f acc[4] = {};
    spmm_mfma_pipe<4>(si, ei, E, ep, yb, W, W + 4096, W + 8192, W + 9216, lane, acc);

#pragma unroll
    for (int h = 0; h < 4; ++h) {
        const float bv = bias[h * 16 + m];
#pragma unroll
        for (int r = 0; r < 4; ++r) {
            const int orow = r0 + q * 4 + r;
            if (orow < N) outp[(size_t)orow * 64 + h * 16 + m] = acc[h][r] + bv;
        }
    }
}

// ---------------------------------------------------------------------------
extern "C" void kernel_launch(void* const* d_in, const int* in_sizes, int n_in,
                              void* d_out, int out_size, void* d_ws, size_t ws_size,
                              hipStream_t stream) {
    const float* x    = (const float*)d_in[0];
    const int*   arow = (const int*)d_in[1];
    const int*   acol = (const int*)d_in[2];
    const float* aval = (const float*)d_in[3];
    const float* w1   = (const float*)d_in[4];
    const float* b1   = (const float*)d_in[5];
    const float* w2   = (const float*)d_in[6];
    const float* b2   = (const float*)d_in[7];
    float*       out  = (float*)d_out;

    const int N = in_sizes[0] / 128;   // 100000
    const int E = in_sizes[1];         // 1600000
    const int B = (N + 127) >> 7;      // 782 buckets of 128 rows

    char* p = (char*)d_ws;
    auto alloc = [&](size_t bytes) {
        char* r = p;
        p += (bytes + 255) & ~(size_t)255;
        return r;
    };
    int*            counts  = (int*)alloc((size_t)MAXB * 4);
    int*            boff    = (int*)alloc((size_t)(MAXB + 1) * 4);
    int*            gcursor = (int*)alloc((size_t)MAXB * 4);
    int*            rowptr  = (int*)alloc((size_t)(N + 1) * 4);
    int2*           epkS    = (int2*)alloc((size_t)(E + 32) * 8);
    unsigned short* w1T     = (unsigned short*)alloc(128 * 128 * 2);
    unsigned short* w2T     = (unsigned short*)alloc(64 * 128 * 2);
    unsigned short* y1b     = (unsigned short*)alloc((size_t)N * 128 * 2);
    int2*           epk     = (int2*)alloc((size_t)E * 8);
    unsigned short* y2b     = (unsigned short*)alloc((size_t)N * 64 * 2);

    const int gemm_blocks = (N + 63) / 64;   // 1563
    const int pb = (E + 4095) / 4096;        // 391

    hipMemsetAsync(counts, 0, (size_t)MAXB * 4, stream);
    hist_prep<<<pb, 256, 0, stream>>>(arow, counts, E, B, w1, w2, w1T, w2T,
                                      rowptr, epkS, N);
    scan_s<<<1, 256, 0, stream>>>(counts, boff, gcursor, B, E);
    partition_k<<<pb, 256, 0, stream>>>(arow, acol, aval, gcursor, epk, E, B);
    sort_gemm1<<<B + gemm_blocks, 256, 0, stream>>>(boff, epk, epkS, rowptr, N, B,
                                                    x, w1T, y1b);
    const int sg2_blocks = (N + 31) / 32;    // 3125, 128-thread blocks
    spmm_gemm2<<<sg2_blocks, 128, 0, stream>>>(rowptr, epkS, y1b, b1, w2T, y2b, N, E);
    spmm64<<<gemm_blocks, 256, 0, stream>>>(rowptr, epkS, y2b, b2, out, N, E);
}